// Round 6
// baseline (1993.366 us; speedup 1.0000x reference)
//
#include <hip/hip_runtime.h>

typedef unsigned short u16;
typedef unsigned int u32;
typedef __bf16 bf16x8 __attribute__((ext_vector_type(8)));
typedef float f32x4 __attribute__((ext_vector_type(4)));

#define ND 512
#define DWR 300
#define DWP 320
#define NCLS 13

__device__ __forceinline__ float bf2f(u16 u) { return __uint_as_float(((u32)u) << 16); }
__device__ __forceinline__ u16 f2bf(float f) {
    u32 u = __float_as_uint(f);
    u32 r = (u + 0x7FFFu + ((u >> 16) & 1u)) >> 16;
    return (u16)r;
}
__device__ __forceinline__ u32 encf(float x) {
    int i = __float_as_int(x);
    return (i < 0) ? ~(u32)i : ((u32)i | 0x80000000u);
}
__device__ __forceinline__ float decf(u32 u) {
    int i = (u & 0x80000000u) ? (int)(u & 0x7FFFFFFFu) : (int)~u;
    return __int_as_float(i);
}
__device__ __forceinline__ void ld8f(const u16* p, float* v) {
    union { float4 f; u16 u[8]; } U;
    U.f = *(const float4*)p;
#pragma unroll
    for (int k = 0; k < 8; ++k) v[k] = bf2f(U.u[k]);
}
__device__ __forceinline__ void ld16(const float* p, float* s) {
    const float4* sp = (const float4*)p;
    float4 s0 = sp[0], s1 = sp[1], s2 = sp[2], s3 = sp[3];
    s[0]=s0.x; s[1]=s0.y; s[2]=s0.z; s[3]=s0.w; s[4]=s1.x; s[5]=s1.y; s[6]=s1.z; s[7]=s1.w;
    s[8]=s2.x; s[9]=s2.y; s[10]=s2.z; s[11]=s2.w; s[12]=s3.x; s[13]=s3.y; s[14]=s3.z; s[15]=s3.w;
}
// bijective 1-D XCD swizzle: consecutive result ids share an XCD
__device__ __forceinline__ int xcd_swz(int b, int gx) {
    const int q = gx >> 3, r = gx & 7;
    const int x = b & 7, o = b >> 3;
    return (x < r ? x * (q + 1) : r * (q + 1) + (x - r) * q) + o;
}

struct GSeg { const u16* base; const int* idx; int stride; int width; };
struct GSegs { GSeg s[5]; };
struct TSeg { int src_begin; int wreal; int wpad; };
struct TSegs { TSeg t[5]; };

// ---------------- node-domain gather-GEMM: C = [relu](A @ BT^T + bias), bf16 out ----------------
template<int RELU>
__global__ __launch_bounds__(256) void gemm_k(
    int M, int Nout, GSegs segs,
    const u16* __restrict__ BT, int ldb,
    const float* __restrict__ bias, int bias_n,
    u16* __restrict__ outb, int ldo)
{
    __shared__ __align__(16) u16 As[128 * 40];
    __shared__ __align__(16) u16 Bs[128 * 40];
    const int tid = threadIdx.x;

    const int gx = gridDim.x, gy = gridDim.y;
    const int g0 = blockIdx.x + gx * blockIdx.y;
    int xt, yt;
    {
        const int fullg = gx >> 3;
        const int gsz = 8 * gy;
        if (g0 < fullg * gsz) {
            const int grp = g0 / gsz, w = g0 % gsz;
            xt = grp * 8 + (w & 7); yt = w >> 3;
        } else {
            const int remx = gx - fullg * 8;
            const int t = g0 - fullg * gsz;
            xt = fullg * 8 + t % remx; yt = t / remx;
        }
    }
    const int m0 = xt * 128, n0 = yt * 128;

    const int row = tid >> 1, half = tid & 1;
    int mrow = m0 + row; if (mrow >= M) mrow = M - 1;
    const int lane = tid & 63, wid = tid >> 6;
    const int wr = (wid >> 1) * 64, wc = (wid & 1) * 64;
    const int lr = lane & 15, lg = lane >> 4;

    f32x4 acc[4][4];
    for (int fm = 0; fm < 4; fm++)
        for (int fn = 0; fn < 4; fn++)
            acc[fm][fn] = f32x4{0.f, 0.f, 0.f, 0.f};

    const u16* brow = BT + (size_t)(n0 + row) * ldb + half * 16;

    auto do_step = [&](const u16* ga_, const u16* gb_) {
        float4 a0 = *(const float4*)ga_;
        float4 a1 = *(const float4*)(ga_ + 8);
        float4 b0 = *(const float4*)gb_;
        float4 b1 = *(const float4*)(gb_ + 8);
        __syncthreads();
        *(float4*)&As[row * 40 + half * 16]     = a0;
        *(float4*)&As[row * 40 + half * 16 + 8] = a1;
        *(float4*)&Bs[row * 40 + half * 16]     = b0;
        *(float4*)&Bs[row * 40 + half * 16 + 8] = b1;
        __syncthreads();
        bf16x8 af[4], bfv[4];
#pragma unroll
        for (int f = 0; f < 4; f++) {
            af[f]  = *(const bf16x8*)&As[(wr + f * 16 + lr) * 40 + lg * 8];
            bfv[f] = *(const bf16x8*)&Bs[(wc + f * 16 + lr) * 40 + lg * 8];
        }
#pragma unroll
        for (int fm = 0; fm < 4; fm++)
#pragma unroll
            for (int fn = 0; fn < 4; fn++)
                acc[fm][fn] = __builtin_amdgcn_mfma_f32_16x16x32_bf16(af[fm], bfv[fn], acc[fm][fn], 0, 0, 0);
    };

    int k0 = 0;
#pragma unroll
    for (int sI = 0; sI < 5; sI++) {
        const GSeg S = segs.s[sI];
        if (S.width > 0) {
            const int ridx = S.idx ? S.idx[mrow] : mrow;
            const u16* abase = S.base + (size_t)ridx * S.stride + half * 16;
            for (int kk = 0; kk < S.width; kk += 32) {
                do_step(abase + kk, brow + k0 + kk);
            }
            k0 += S.width;
        }
    }

#pragma unroll
    for (int fm = 0; fm < 4; fm++) {
#pragma unroll
        for (int i = 0; i < 4; i++) {
            const int grow = m0 + wr + fm * 16 + lg * 4 + i;
            const bool rok = grow < M;
#pragma unroll
            for (int fn = 0; fn < 4; fn++) {
                const int col = n0 + wc + fn * 16 + lr;
                float v = acc[fm][fn][i];
                v += (col < bias_n) ? bias[col] : 0.f;
                if (RELU) v = fmaxf(v, 0.f);
                if (rok && col < Nout) outb[(size_t)grow * ldo + col] = f2bf(v);
            }
        }
    }
}

// ---------------- per-edge pass 1: attention logits (2-edge pipeline) ----------------
__global__ __launch_bounds__(256) void pass1_k(
    const u16* __restrict__ Q, const u16* __restrict__ Lq,
    const float* __restrict__ s_f, const float* __restrict__ wmid,
    const int* __restrict__ psrc, const int* __restrict__ pdst, const int* __restrict__ perm,
    const float* __restrict__ W_a, const float* __restrict__ W_al,
    const float* __restrict__ b_e, const float* __restrict__ b_el,
    const float* __restrict__ b_a, const float* __restrict__ b_al,
    float* __restrict__ aA, float* __restrict__ aL, int E)
{
    __shared__ __align__(16) u16 wmids[16 * 512];
    const int tid = threadIdx.x;
    for (int i = tid; i < 16 * 512; i += 256) wmids[i] = f2bf(wmid[i]);
    __syncthreads();
    const int lane = tid & 63;
    const int col0 = lane * 8;
    float wa[8], wal[8], be[8], bel[8];
#pragma unroll
    for (int k = 0; k < 8; ++k) {
        wa[k] = W_a[col0 + k]; wal[k] = W_al[col0 + k];
        be[k] = b_e[col0 + k]; bel[k] = b_el[col0 + k];
    }
    const float ba = b_a[0], bal = b_al[0];
    const int gw = xcd_swz(blockIdx.x, gridDim.x) * 4 + (tid >> 6);
    const int nw = gridDim.x * 4;
    for (int eA = gw * 2; eA < E; eA += nw * 2) {
        const int eB = (eA + 1 < E) ? eA + 1 : eA;
        const int psA = psrc[eA], pdA = pdst[eA], peA = perm[eA];
        const int psB = psrc[eB], pdB = pdst[eB], peB = perm[eB];
        float sfA[16], sfB[16];
        ld16(s_f + (size_t)peA * 16, sfA);
        ld16(s_f + (size_t)peB * 16, sfB);
        float vA[8], vB[8], t1[8], t2[8];
        ld8f(Q + (size_t)psA * 1024 + col0, t1);
        ld8f(Q + (size_t)pdA * 1024 + 512 + col0, t2);
#pragma unroll
        for (int k = 0; k < 8; ++k) vA[k] = t1[k] + t2[k] + be[k];
        ld8f(Q + (size_t)psB * 1024 + col0, t1);
        ld8f(Q + (size_t)pdB * 1024 + 512 + col0, t2);
#pragma unroll
        for (int k = 0; k < 8; ++k) vB[k] = t1[k] + t2[k] + be[k];
#pragma unroll
        for (int j = 0; j < 16; ++j) {
            union { float4 f; u16 u[8]; } W;
            W.f = *(const float4*)&wmids[j * 512 + col0];
#pragma unroll
            for (int k = 0; k < 8; ++k) {
                const float w = bf2f(W.u[k]);
                vA[k] = fmaf(sfA[j], w, vA[k]);
                vB[k] = fmaf(sfB[j], w, vB[k]);
            }
        }
        float apA = 0.f, apB = 0.f;
#pragma unroll
        for (int k = 0; k < 8; ++k) {
            apA = fmaf(fmaxf(vA[k], 0.f), wa[k], apA);
            apB = fmaf(fmaxf(vB[k], 0.f), wa[k], apB);
        }
        // lang path
        ld8f(Lq + (size_t)psA * 1024 + col0, t1);
        ld8f(Lq + (size_t)pdA * 1024 + 512 + col0, t2);
        float alA = 0.f, alB = 0.f;
#pragma unroll
        for (int k = 0; k < 8; ++k) alA = fmaf(fmaxf(t1[k] + t2[k] + bel[k], 0.f), wal[k], alA);
        ld8f(Lq + (size_t)psB * 1024 + col0, t1);
        ld8f(Lq + (size_t)pdB * 1024 + 512 + col0, t2);
#pragma unroll
        for (int k = 0; k < 8; ++k) alB = fmaf(fmaxf(t1[k] + t2[k] + bel[k], 0.f), wal[k], alB);
#pragma unroll
        for (int off = 32; off >= 1; off >>= 1) {
            apA += __shfl_xor(apA, off, 64);
            apB += __shfl_xor(apB, off, 64);
            alA += __shfl_xor(alA, off, 64);
            alB += __shfl_xor(alB, off, 64);
        }
        if (lane == 0) {
            float x = apA + ba;  aA[eA] = x > 0.f ? x : 0.2f * x;
            float y = alA + bal; aL[eA] = y > 0.f ? y : 0.2f * y;
            if (eB != eA) {
                float x2 = apB + ba;  aA[eB] = x2 > 0.f ? x2 : 0.2f * x2;
                float y2 = alB + bal; aL[eB] = y2 > 0.f ? y2 : 0.2f * y2;
            }
        }
    }
}

// ---------------- per-node pass 2: z aggregation (2-edge pipeline) ----------------
__global__ __launch_bounds__(256) void pass2_k(
    const u16* __restrict__ Q, const float* __restrict__ s_f, const float* __restrict__ wmid,
    const int* __restrict__ psrc, const int* __restrict__ perm, const int* __restrict__ offs,
    const float* __restrict__ alpha, const float* __restrict__ b_e,
    u16* __restrict__ z_bf, int N, int E)
{
    __shared__ __align__(16) u16 wmids[16 * 512];
    const int tid = threadIdx.x;
    for (int i = tid; i < 16 * 512; i += 256) wmids[i] = f2bf(wmid[i]);
    __syncthreads();
    const int node = blockIdx.x * 4 + (tid >> 6);
    if (node >= N) return;
    const int lane = tid & 63;
    const int col0 = lane * 8;
    float q2[8], be[8], acc[8];
    ld8f(Q + (size_t)node * 1024 + 512 + col0, q2);
#pragma unroll
    for (int k = 0; k < 8; ++k) { be[k] = b_e[col0 + k]; acc[k] = 0.f; }
    const int e0 = offs[node];
    const int e1 = (node + 1 < N) ? offs[node + 1] : E;
    int e = e0;
    for (; e + 1 < e1; e += 2) {
        const float alA = alpha[e], alB = alpha[e + 1];
        const int psA = psrc[e], peA = perm[e];
        const int psB = psrc[e + 1], peB = perm[e + 1];
        float sfA[16], sfB[16];
        ld16(s_f + (size_t)peA * 16, sfA);
        ld16(s_f + (size_t)peB * 16, sfB);
        float vA[8], vB[8], t1[8];
        ld8f(Q + (size_t)psA * 1024 + col0, t1);
#pragma unroll
        for (int k = 0; k < 8; ++k) vA[k] = t1[k] + q2[k] + be[k];
        ld8f(Q + (size_t)psB * 1024 + col0, t1);
#pragma unroll
        for (int k = 0; k < 8; ++k) vB[k] = t1[k] + q2[k] + be[k];
#pragma unroll
        for (int j = 0; j < 16; ++j) {
            union { float4 f; u16 u[8]; } W;
            W.f = *(const float4*)&wmids[j * 512 + col0];
#pragma unroll
            for (int k = 0; k < 8; ++k) {
                const float w = bf2f(W.u[k]);
                vA[k] = fmaf(sfA[j], w, vA[k]);
                vB[k] = fmaf(sfB[j], w, vB[k]);
            }
        }
#pragma unroll
        for (int k = 0; k < 8; ++k)
            acc[k] += alA * fmaxf(vA[k], 0.f) + alB * fmaxf(vB[k], 0.f);
    }
    for (; e < e1; ++e) {
        const float al = alpha[e];
        const int ps = psrc[e], pe = perm[e];
        float sfv[16];
        ld16(s_f + (size_t)pe * 16, sfv);
        float v[8], q1[8];
        ld8f(Q + (size_t)ps * 1024 + col0, q1);
#pragma unroll
        for (int k = 0; k < 8; ++k) v[k] = q1[k] + q2[k] + be[k];
#pragma unroll
        for (int j = 0; j < 16; ++j) {
            union { float4 f; u16 u[8]; } W;
            W.f = *(const float4*)&wmids[j * 512 + col0];
#pragma unroll
            for (int k = 0; k < 8; ++k) v[k] = fmaf(sfv[j], bf2f(W.u[k]), v[k]);
        }
#pragma unroll
        for (int k = 0; k < 8; ++k) acc[k] = fmaf(al, fmaxf(v[k], 0.f), acc[k]);
    }
    union { float4 f; u16 u[8]; } O;
#pragma unroll
    for (int k = 0; k < 8; ++k) O.u[k] = f2bf(acc[k]);
    *(float4*)(z_bf + (size_t)node * 512 + col0) = O.f;
}

// ---------------- per-edge pass 3: readout (2-edge pipeline) ----------------
__global__ __launch_bounds__(256) void pass3_k(
    const u16* __restrict__ P, const float* __restrict__ s_f, const float* __restrict__ wmid2,
    const int* __restrict__ psrc, const int* __restrict__ pdst, const int* __restrict__ perm,
    const float* __restrict__ b_r1, const float* __restrict__ w2, const float* __restrict__ b_r2,
    float* __restrict__ out, int E)
{
    __shared__ __align__(16) u16 wmids[16 * 512];
    __shared__ __align__(16) u16 w2Ts[NCLS * 512];
    const int tid = threadIdx.x;
    for (int i = tid; i < 16 * 512; i += 256) wmids[i] = f2bf(wmid2[i]);
    for (int i = tid; i < NCLS * 512; i += 256) {
        const int c = i >> 9, col = i & 511;
        w2Ts[i] = f2bf(w2[col * NCLS + c]);
    }
    __syncthreads();
    const int lane = tid & 63;
    const int col0 = lane * 8;
    float br[8];
#pragma unroll
    for (int k = 0; k < 8; ++k) br[k] = b_r1[col0 + k];
    const int gw = xcd_swz(blockIdx.x, gridDim.x) * 4 + (tid >> 6);
    const int nw = gridDim.x * 4;
    for (int eA = gw * 2; eA < E; eA += nw * 2) {
        const int eB = (eA + 1 < E) ? eA + 1 : eA;
        const int psA = psrc[eA], pdA = pdst[eA], peA = perm[eA];
        const int psB = psrc[eB], pdB = pdst[eB], peB = perm[eB];
        float sfA[16], sfB[16];
        ld16(s_f + (size_t)peA * 16, sfA);
        ld16(s_f + (size_t)peB * 16, sfB);
        float vA[8], vB[8], t1[8], t2[8];
        ld8f(P + (size_t)psA * 1024 + col0, t1);
        ld8f(P + (size_t)pdA * 1024 + 512 + col0, t2);
#pragma unroll
        for (int k = 0; k < 8; ++k) vA[k] = t1[k] + t2[k] + br[k];
        ld8f(P + (size_t)psB * 1024 + col0, t1);
        ld8f(P + (size_t)pdB * 1024 + 512 + col0, t2);
#pragma unroll
        for (int k = 0; k < 8; ++k) vB[k] = t1[k] + t2[k] + br[k];
#pragma unroll
        for (int j = 0; j < 16; ++j) {
            union { float4 f; u16 u[8]; } W;
            W.f = *(const float4*)&wmids[j * 512 + col0];
#pragma unroll
            for (int k = 0; k < 8; ++k) {
                const float w = bf2f(W.u[k]);
                vA[k] = fmaf(sfA[j], w, vA[k]);
                vB[k] = fmaf(sfB[j], w, vB[k]);
            }
        }
#pragma unroll
        for (int k = 0; k < 8; ++k) {
            vA[k] = fmaxf(vA[k], 0.f);
            vB[k] = fmaxf(vB[k], 0.f);
        }
#pragma unroll
        for (int c = 0; c < NCLS; ++c) {
            union { float4 f; u16 u[8]; } W;
            W.f = *(const float4*)&w2Ts[c * 512 + col0];
            float tA = 0.f, tB = 0.f;
#pragma unroll
            for (int k = 0; k < 8; ++k) {
                const float w = bf2f(W.u[k]);
                tA = fmaf(vA[k], w, tA);
                tB = fmaf(vB[k], w, tB);
            }
#pragma unroll
            for (int off = 32; off >= 1; off >>= 1) {
                tA += __shfl_xor(tA, off, 64);
                tB += __shfl_xor(tB, off, 64);
            }
            if (lane == 0) {
                const float bc = b_r2[c];
                out[(size_t)peA * NCLS + c] = tA + bc;
                if (eB != eA) out[(size_t)peB * NCLS + c] = tB + bc;
            }
        }
    }
}

// ---------------- small kernels ----------------
__global__ __launch_bounds__(256) void cvt_bf(const float* __restrict__ src, u16* __restrict__ dst,
                                              int R, int Cs, int Cd)
{
    int id = blockIdx.x * 256 + threadIdx.x;
    if (id >= R * Cd) return;
    int r = id / Cd, c = id % Cd;
    float v = (c < Cs) ? src[(size_t)r * Cs + c] : 0.f;
    dst[id] = f2bf(v);
}

__global__ __launch_bounds__(256) void wtrans(const float* __restrict__ W, int Nw, int Nreal,
                                              int NrowsOut, int ldk, TSegs ts, int nseg,
                                              u16* __restrict__ WT)
{
    int id = blockIdx.x * 256 + threadIdx.x;
    if (id >= NrowsOut * ldk) return;
    int n = id / ldk, kp = id % ldk;
    float v = 0.f;
    if (n < Nreal) {
        int off = 0;
#pragma unroll
        for (int s = 0; s < 5; s++) {
            if (s < nseg) {
                int kl = kp - off;
                if (kl >= 0 && kl < ts.t[s].wpad) {
                    if (kl < ts.t[s].wreal) v = W[(size_t)(ts.t[s].src_begin + kl) * Nw + n];
                }
                off += ts.t[s].wpad;
            }
        }
    }
    WT[id] = f2bf(v);
}

__global__ __launch_bounds__(256) void hist_k(const int* __restrict__ dst, int* __restrict__ deg, int E)
{
    int id = blockIdx.x * 256 + threadIdx.x;
    if (id < E) atomicAdd(&deg[dst[id]], 1);
}

__global__ __launch_bounds__(1024) void scan_k(const int* __restrict__ deg,
                                               int* __restrict__ offs, int* __restrict__ cursor, int N)
{
    __shared__ int ps[1024];
    const int t = threadIdx.x;
    const int per = (N + 1023) >> 10;
    int s = 0;
    for (int j = 0; j < per; j++) { int idx = t * per + j; if (idx < N) s += deg[idx]; }
    ps[t] = s; __syncthreads();
    for (int o = 1; o < 1024; o <<= 1) {
        int v = (t >= o) ? ps[t - o] : 0; __syncthreads();
        ps[t] += v; __syncthreads();
    }
    int run = ps[t] - s;
    for (int j = 0; j < per; j++) {
        int idx = t * per + j;
        if (idx < N) { offs[idx] = run; cursor[idx] = run; run += deg[idx]; }
    }
}

__global__ __launch_bounds__(256) void scat_perm_k(const int* __restrict__ src, const int* __restrict__ dst,
                                                   int* __restrict__ cursor, int* __restrict__ perm,
                                                   int* __restrict__ psrc, int* __restrict__ pdst, int E)
{
    int id = blockIdx.x * 256 + threadIdx.x;
    if (id >= E) return;
    int d = dst[id];
    int pos = atomicAdd(&cursor[d], 1);
    perm[pos] = id; psrc[pos] = src[id]; pdst[pos] = d;
}

__global__ __launch_bounds__(256) void segmax_k(const float* a, const float* al, const int* seg,
                                                u32* mu, u32* ml, int E)
{
    int id = blockIdx.x * 256 + threadIdx.x;
    if (id >= E) return;
    int d = seg[id];
    atomicMax(&mu[d], encf(a[id]));
    atomicMax(&ml[d], encf(al[id]));
}

__global__ __launch_bounds__(256) void expsum_k(float* a, float* al, const int* seg,
                                                const u32* mu, const u32* ml,
                                                float* s, float* sl, int E)
{
    int id = blockIdx.x * 256 + threadIdx.x;
    if (id >= E) return;
    int d = seg[id];
    float v = expf(a[id] - decf(mu[d]));  a[id] = v;  atomicAdd(&s[d], v);
    float w = expf(al[id] - decf(ml[d])); al[id] = w; atomicAdd(&sl[d], w);
}

__global__ __launch_bounds__(256) void alpha_k(float* a, float* al, const int* seg,
                                               const float* s, const float* sl, int E)
{
    int id = blockIdx.x * 256 + threadIdx.x;
    if (id >= E) return;
    int d = seg[id];
    a[id]  = a[id]  / (s[d]  + 1e-9f);
    al[id] = al[id] / (sl[d] + 1e-9f);
}

__global__ __launch_bounds__(256) void agg_zl_seg(const u16* __restrict__ wv_bf,
                                                  const float* __restrict__ alphal,
                                                  const int* __restrict__ psrc,
                                                  const int* __restrict__ offs,
                                                  float* __restrict__ zl, int N, int E)
{
    const int node = blockIdx.x * 4 + (threadIdx.x >> 6);
    const int lane = threadIdx.x & 63;
    if (node >= N) return;
    const int e0 = offs[node];
    const int e1 = (node + 1 < N) ? offs[node + 1] : E;
    float acc[5] = {0.f, 0.f, 0.f, 0.f, 0.f};
    int e = e0;
    for (; e + 1 < e1; e += 2) {
        const float alA = alphal[e], alB = alphal[e + 1];
        const u16* wrA = wv_bf + (size_t)psrc[e] * DWP;
        const u16* wrB = wv_bf + (size_t)psrc[e + 1] * DWP;
#pragma unroll
        for (int j = 0; j < 5; ++j)
            acc[j] += alA * bf2f(wrA[lane + 64 * j]) + alB * bf2f(wrB[lane + 64 * j]);
    }
    for (; e < e1; ++e) {
        const float al = alphal[e];
        const u16* wr = wv_bf + (size_t)psrc[e] * DWP;
#pragma unroll
        for (int j = 0; j < 5; ++j) acc[j] += al * bf2f(wr[lane + 64 * j]);
    }
#pragma unroll
    for (int j = 0; j < 5; ++j) {
        const int c = lane + 64 * j;
        if (c < DWR) zl[(size_t)node * DWR + c] = acc[j];
    }
}

__global__ __launch_bounds__(256) void diag_fill(float* out, int n, float v)
{
    int id = blockIdx.x * 256 + threadIdx.x;
    if (id < n) out[id] = v;
}

// ---------------- host ----------------
extern "C" void kernel_launch(void* const* d_in, const int* in_sizes, int n_in,
                              void* d_out, int out_size, void* d_ws, size_t ws_size,
                              hipStream_t stream)
{
    const float* n_f  = (const float*)d_in[0];
    const float* w2v  = (const float*)d_in[1];
    const float* s_f  = (const float*)d_in[2];
    const int*   src  = (const int*)d_in[3];
    const int*   dst  = (const int*)d_in[4];
    const float* W_e  = (const float*)d_in[5];
    const float* b_e  = (const float*)d_in[6];
    const float* W_el = (const float*)d_in[7];
    const float* b_el = (const float*)d_in[8];
    const float* W_a  = (const float*)d_in[9];
    const float* b_a  = (const float*)d_in[10];
    const float* W_al = (const float*)d_in[11];
    const float* b_al = (const float*)d_in[12];
    const float* W_n  = (const float*)d_in[13];
    const float* b_n  = (const float*)d_in[14];
    const float* W_nl = (const float*)d_in[15];
    const float* b_nl = (const float*)d_in[16];
    const float* W_r1 = (const float*)d_in[17];
    const float* b_r1 = (const float*)d_in[18];
    const float* W_r2 = (const float*)d_in[19];
    const float* b_r2 = (const float*)d_in[20];

    const int N = in_sizes[0] / ND;   // 20000
    const int E = in_sizes[3];        // 320000
    float* out = (float*)d_out;

    auto g1 = [](long long n) { return dim3((unsigned)((n + 255) / 256)); };

    char* base = (char*)d_ws;
    size_t off = 0;
    auto alloc = [&](size_t bytes) -> void* {
        void* r = base + off;
        off += (bytes + 255) & ~(size_t)255;
        return r;
    };
    u16* nf_bf = (u16*)alloc((size_t)N * ND * 2);
    u16* wv_bf = (u16*)alloc((size_t)N * DWP * 2);
    u16* Q     = (u16*)alloc((size_t)N * 1024 * 2);
    u16* Lq    = (u16*)alloc((size_t)N * 1024 * 2);
    u16* Pt    = (u16*)alloc((size_t)N * 1024 * 2);
    u16* z_bf  = (u16*)alloc((size_t)N * ND * 2);
    u16* zl_bf = (u16*)alloc((size_t)N * DWP * 2);
    u16* nn_bf = (u16*)alloc((size_t)N * ND * 2);
    float* zl  = (float*)alloc((size_t)N * DWR * 4);
    u16* QT    = (u16*)alloc((size_t)1024 * 512 * 2);
    u16* LT    = (u16*)alloc((size_t)1024 * 320 * 2);
    u16* WnT   = (u16*)alloc((size_t)512 * 1024 * 2);
    u16* WnlT  = (u16*)alloc((size_t)384 * 640 * 2);
    u16* PrT   = (u16*)alloc((size_t)1024 * 832 * 2);
    float* aAs = (float*)alloc((size_t)E * 4);
    float* aLs = (float*)alloc((size_t)E * 4);
    float* sD  = (float*)alloc((size_t)N * 4);
    float* sLd = (float*)alloc((size_t)N * 4);
    u32* mU    = (u32*)alloc((size_t)N * 4);
    u32* mL    = (u32*)alloc((size_t)N * 4);
    int* deg    = (int*)alloc((size_t)N * 4);
    int* offs   = (int*)alloc((size_t)N * 4);
    int* cursor = (int*)alloc((size_t)N * 4);
    int* perm   = (int*)alloc((size_t)E * 4);
    int* psrc   = (int*)alloc((size_t)E * 4);
    int* pdst   = (int*)alloc((size_t)E * 4);
    // lifetime aliasing: zl (f32) dead after cvt -> reuse for wn_bf
    u16* wn_bf = (u16*)zl;

    if (off > ws_size) {
        diag_fill<<<g1(out_size), 256, 0, stream>>>(out, out_size, 2.0e6f);
        return;
    }

    hipMemsetAsync(sD,  0, (size_t)N * 4, stream);
    hipMemsetAsync(sLd, 0, (size_t)N * 4, stream);
    hipMemsetAsync(mU,  0, (size_t)N * 4, stream);
    hipMemsetAsync(mL,  0, (size_t)N * 4, stream);
    hipMemsetAsync(deg, 0, (size_t)N * 4, stream);

    // sort edges by dst
    hist_k<<<g1(E), 256, 0, stream>>>(dst, deg, E);
    scan_k<<<dim3(1), 1024, 0, stream>>>(deg, offs, cursor, N);
    scat_perm_k<<<g1(E), 256, 0, stream>>>(src, dst, cursor, perm, psrc, pdst, E);

    cvt_bf<<<g1((long long)N * ND), 256, 0, stream>>>(n_f, nf_bf, N, ND, ND);
    cvt_bf<<<g1((long long)N * DWP), 256, 0, stream>>>(w2v, wv_bf, N, DWR, DWP);

    // weight prep
    { TSegs t{}; t.t[0] = {0,512,512};
      wtrans<<<g1(512 * 512), 256, 0, stream>>>(W_e, 512, 512, 512, 512, t, 1, QT); }
    { TSegs t{}; t.t[0] = {528,512,512};
      wtrans<<<g1(512 * 512), 256, 0, stream>>>(W_e, 512, 512, 512, 512, t, 1, QT + 512 * 512); }
    { TSegs t{}; t.t[0] = {0,300,320};
      wtrans<<<g1(512 * 320), 256, 0, stream>>>(W_el, 512, 512, 512, 320, t, 1, LT); }
    { TSegs t{}; t.t[0] = {300,300,320};
      wtrans<<<g1(512 * 320), 256, 0, stream>>>(W_el, 512, 512, 512, 320, t, 1, LT + 512 * 320); }
    { TSegs t{}; t.t[0] = {0,512,512}; t.t[1] = {512,512,512};
      wtrans<<<g1(512 * 1024), 256, 0, stream>>>(W_n, 512, 512, 512, 1024, t, 2, WnT); }
    { TSegs t{}; t.t[0] = {0,300,320}; t.t[1] = {300,300,320};
      wtrans<<<g1(384 * 640), 256, 0, stream>>>(W_nl, 300, 300, 384, 640, t, 2, WnlT); }
    { TSegs t{}; t.t[0] = {0,512,512}; t.t[1] = {512,300,320};
      wtrans<<<g1(512 * 832), 256, 0, stream>>>(W_r1, 512, 512, 512, 832, t, 2, PrT); }
    { TSegs t{}; t.t[0] = {1128,512,512}; t.t[1] = {828,300,320};
      wtrans<<<g1(512 * 832), 256, 0, stream>>>(W_r1, 512, 512, 512, 832, t, 2, PrT + 512 * 832); }

    const int gmx = (N + 127) / 128;

    // node projections Q, L
    { GSegs s{}; s.s[0] = {nf_bf, nullptr, ND, 512};
      gemm_k<0><<<dim3(gmx, 8), 256, 0, stream>>>(N, 1024, s, QT, 512, nullptr, 0, Q, 1024); }
    { GSegs s{}; s.s[0] = {wv_bf, nullptr, DWP, 320};
      gemm_k<0><<<dim3(gmx, 8), 256, 0, stream>>>(N, 1024, s, LT, 320, nullptr, 0, Lq, 1024); }

    // attention logits
    pass1_k<<<dim3(2048), 256, 0, stream>>>(Q, Lq, s_f, W_e + 512 * 512, psrc, pdst, perm,
                                            W_a, W_al, b_e, b_el, b_a, b_al, aAs, aLs, E);
    segmax_k<<<g1(E), 256, 0, stream>>>(aAs, aLs, pdst, mU, mL, E);
    expsum_k<<<g1(E), 256, 0, stream>>>(aAs, aLs, pdst, mU, mL, sD, sLd, E);
    alpha_k<<<g1(E), 256, 0, stream>>>(aAs, aLs, pdst, sD, sLd, E);

    // aggregations
    pass2_k<<<dim3((N + 3) / 4), 256, 0, stream>>>(Q, s_f, W_e + 512 * 512, psrc, perm, offs,
                                                   aAs, b_e, z_bf, N, E);
    agg_zl_seg<<<dim3((N + 3) / 4), 256, 0, stream>>>(wv_bf, aLs, psrc, offs, zl, N, E);
    cvt_bf<<<g1((long long)N * DWP), 256, 0, stream>>>(zl, zl_bf, N, DWR, DWP);

    // node MLPs
    { GSegs s{}; s.s[0] = {nf_bf, nullptr, ND, 512}; s.s[1] = {z_bf, nullptr, ND, 512};
      gemm_k<1><<<dim3(gmx, 4), 256, 0, stream>>>(N, 512, s, WnT, 1024, b_n, 512, nn_bf, 512); }
    { GSegs s{}; s.s[0] = {wv_bf, nullptr, DWP, 320}; s.s[1] = {zl_bf, nullptr, DWP, 320};
      gemm_k<1><<<dim3(gmx, 3), 256, 0, stream>>>(N, 320, s, WnlT, 640, b_nl, 300, wn_bf, DWP); }

    // readout projection P
    { GSegs s{}; s.s[0] = {nn_bf, nullptr, ND, 512}; s.s[1] = {wn_bf, nullptr, DWP, 320};
      gemm_k<0><<<dim3(gmx, 8), 256, 0, stream>>>(N, 1024, s, PrT, 832, nullptr, 0, Pt, 1024); }

    // readout per-edge pass (includes b_r2, writes original order)
    pass3_k<<<dim3(2048), 256, 0, stream>>>(Pt, s_f, W_r1 + 812 * 512, psrc, pdst, perm,
                                            b_r1, W_r2, b_r2, out, E);

    hipError_t e = hipGetLastError();
    if (e != hipSuccess) {
        diag_fill<<<g1(out_size), 256, 0, stream>>>(out, out_size, 1.0e6f + (float)(int)e);
    }
}